// Round 9
// baseline (47.192 us; speedup 1.0000x reference)
//
#include <hip/hip_runtime.h>

// InverseDaubechiesWaveletLayer: polyphase inverse DWT (db4), fused.
// in : [B=16, L=16000, 128] f32 (first 64 ch = approx, last 64 = detail)
// out: [B=16, 2L=32000, 64] f32
//
//   out[2m]   = sum_k z_a[m-1+k]*lo[2k+1] + z_d[m-1+k]*hi[2k+1]
//   out[2m+1] = sum_k z_a[m-1+k]*lo[2k]   + z_d[m-1+k]*hi[2k]   (k=0..3)
//
// R9: MPB=64 (halo 9.4%->4.7%), 512 threads x 2 adjacent m per thread:
//     5 LDS row-reads serve 2 output pairs (vs 8 for 2 in R8), 4 contiguous
//     stores/thread. LDS 34.3KB -> 4 blocks/CU.

#define NB 16
#define NL 16000
#define MPB 64              // m-values per block
#define NMB (NL / MPB)      // 250 m-blocks per batch
#define ROWS (MPB + 3)      // 67 staged rows: m0-1 .. m0+65

typedef float fx4 __attribute__((ext_vector_type(4)));

__global__ __launch_bounds__(512) void idwt_db4_kernel(
    const float* __restrict__ in,
    const float* __restrict__ rec_lo,
    const float* __restrict__ rec_hi,
    float* __restrict__ out)
{
    __shared__ float s[ROWS * 128];   // 34304 B

    const int tid = threadIdx.x;
    const int c  = (tid & 15) * 4;   // channel quad offset 0..60
    const int ml = tid >> 4;         // 0..31: m-pair within block
    const int blk = blockIdx.x;
    const int b = blk / NMB;
    const int m0 = (blk - b * NMB) * MPB;

    float lo[8], hi[8];
#pragma unroll
    for (int i = 0; i < 8; ++i) { lo[i] = rec_lo[i]; hi[i] = rec_hi[i]; }

    // Stage rows m0-1 .. m0+65 (67 rows x 32 quads) -> LDS, coalesced.
    const long rowBase = (long)b * NL * 128;
    for (int i = tid; i < ROWS * 32; i += 512) {
        const int r = i >> 5;        // row 0..66
        const int q = i & 31;        // float4 index within row
        const int l = m0 - 1 + r;
        fx4 v = (fx4)(0.f);
        if (l >= 0 && l < NL)
            v = *(const fx4*)(in + rowBase + (long)l * 128 + q * 4);
        *(fx4*)(&s[r * 128 + q * 4]) = v;
    }
    __syncthreads();

    // This thread: m_a = m0+2*ml, m_b = m_a+1. Rows 2ml..2ml+4 serve both.
    fx4 A[5], D[5];
#pragma unroll
    for (int r = 0; r < 5; ++r) {
        A[r] = *(const fx4*)(&s[(2 * ml + r) * 128 + c]);
        D[r] = *(const fx4*)(&s[(2 * ml + r) * 128 + 64 + c]);
    }

    fx4 ev_a = (fx4)(0.f), od_a = (fx4)(0.f);
    fx4 ev_b = (fx4)(0.f), od_b = (fx4)(0.f);
#pragma unroll
    for (int k = 0; k < 4; ++k) {
        const float leA = lo[2*k + 1], leD = hi[2*k + 1];   // even-t taps
        const float loA = lo[2*k],     loD = hi[2*k];       // odd-t taps
        ev_a = A[k]     * leA + (D[k]     * leD + ev_a);
        od_a = A[k]     * loA + (D[k]     * loD + od_a);
        ev_b = A[k + 1] * leA + (D[k + 1] * leD + ev_b);
        od_b = A[k + 1] * loA + (D[k + 1] * loD + od_b);
    }

    // 4 consecutive output rows: t = 2m_a, 2m_a+1, 2m_a+2, 2m_a+3
    const long outBase = ((long)b * (2 * NL) + 2 * (m0 + 2 * ml)) * 64 + c;
    *(fx4*)(out + outBase)       = ev_a;
    *(fx4*)(out + outBase + 64)  = od_a;
    *(fx4*)(out + outBase + 128) = ev_b;
    *(fx4*)(out + outBase + 192) = od_b;
}

extern "C" void kernel_launch(void* const* d_in, const int* in_sizes, int n_in,
                              void* d_out, int out_size, void* d_ws, size_t ws_size,
                              hipStream_t stream)
{
    const float* in     = (const float*)d_in[0];
    const float* rec_lo = (const float*)d_in[1];
    const float* rec_hi = (const float*)d_in[2];
    float* out = (float*)d_out;

    dim3 grid(NB * NMB);   // 4000 blocks
    dim3 block(512);
    idwt_db4_kernel<<<grid, block, 0, stream>>>(in, rec_lo, rec_hi, out);
}

// Round 10
// 44.969 us; speedup vs baseline: 1.0494x; 1.0494x over previous
//
#include <hip/hip_runtime.h>

// InverseDaubechiesWaveletLayer: polyphase inverse DWT (db4), fused.
// in : [B=16, L=16000, 128] f32 (first 64 ch = approx, last 64 = detail)
// out: [B=16, 2L=32000, 64] f32
//
//   out[2m]   = sum_k z_a[m-1+k]*lo[2k+1] + z_d[m-1+k]*hi[2k+1]
//   out[2m+1] = sum_k z_a[m-1+k]*lo[2k]   + z_d[m-1+k]*hi[2k]   (k=0..3)
//
// FINAL (= R8, best measured 46.65us ~ 89% of 6.29 TB/s mixed-stream ceiling):
// 512-thread blocks, 32 m per block; 35 input rows staged once to LDS
// (coalesced, 9.4% halo); 1 output pair per thread; plain fx4 stores.
// Survey: R1 no-LDS 48.07 | R3 MPT4 85 | R4 MPT2 54.9 | R5 NT 48.30 |
//         R6 const-filters 49.85 | R7 LDS/16m 47.24 | R8 46.65 | R9 64m 47.19.

#define NB 16
#define NL 16000
#define MPB 32              // m-values per block
#define NMB (NL / MPB)      // 500 m-blocks per batch
#define ROWS (MPB + 3)      // 35 staged rows: m0-1 .. m0+33

typedef float fx4 __attribute__((ext_vector_type(4)));

__global__ __launch_bounds__(512) void idwt_db4_kernel(
    const float* __restrict__ in,
    const float* __restrict__ rec_lo,
    const float* __restrict__ rec_hi,
    float* __restrict__ out)
{
    __shared__ float s[ROWS * 128];   // 17920 B

    const int tid = threadIdx.x;
    const int c  = (tid & 15) * 4;   // channel quad offset 0..60
    const int ml = tid >> 4;         // 0..31: m within block
    const int blk = blockIdx.x;
    const int b = blk / NMB;
    const int m0 = (blk - b * NMB) * MPB;
    const int m = m0 + ml;

    float lo[8], hi[8];
#pragma unroll
    for (int i = 0; i < 8; ++i) { lo[i] = rec_lo[i]; hi[i] = rec_hi[i]; }

    // Stage rows m0-1 .. m0+33 (35 rows x 128 floats) -> LDS, coalesced.
    const long rowBase = (long)b * NL * 128;
#pragma unroll
    for (int i = tid; i < ROWS * 32; i += 512) {
        const int r = i >> 5;        // row 0..34
        const int q = i & 31;        // float4 index within row
        const int l = m0 - 1 + r;
        fx4 v = (fx4)(0.f);
        if (l >= 0 && l < NL)
            v = *(const fx4*)(in + rowBase + (long)l * 128 + q * 4);
        *(fx4*)(&s[r * 128 + q * 4]) = v;
    }
    __syncthreads();

    // Window rows for this m: LDS rows ml .. ml+3
    fx4 ev = (fx4)(0.f);
    fx4 od = (fx4)(0.f);
#pragma unroll
    for (int k = 0; k < 4; ++k) {
        const fx4 a = *(const fx4*)(&s[(ml + k) * 128 + c]);
        const fx4 d = *(const fx4*)(&s[(ml + k) * 128 + 64 + c]);
        const float leA = lo[2*k + 1], leD = hi[2*k + 1];   // even-t taps
        const float loA = lo[2*k],     loD = hi[2*k];       // odd-t taps
        ev = a * leA + (d * leD + ev);
        od = a * loA + (d * loD + od);
    }

    const long outBase = ((long)b * (2 * NL) + 2 * m) * 64 + c;
    *(fx4*)(out + outBase)      = ev;   // t = 2m
    *(fx4*)(out + outBase + 64) = od;   // t = 2m+1
}

extern "C" void kernel_launch(void* const* d_in, const int* in_sizes, int n_in,
                              void* d_out, int out_size, void* d_ws, size_t ws_size,
                              hipStream_t stream)
{
    const float* in     = (const float*)d_in[0];
    const float* rec_lo = (const float*)d_in[1];
    const float* rec_hi = (const float*)d_in[2];
    float* out = (float*)d_out;

    dim3 grid(NB * NMB);   // 8000 blocks
    dim3 block(512);
    idwt_db4_kernel<<<grid, block, 0, stream>>>(in, rec_lo, rec_hi, out);
}